// Round 1
// baseline (1143.770 us; speedup 1.0000x reference)
//
#include <hip/hip_runtime.h>
#include <math.h>

#define NN 32000
#define FIN 128
#define HC 256      // HEADS*CH
#define NH 4        // heads
#define HIDD 512
#define BB 64       // batch
#define ZD 64
#define KC 2000     // k-chunk for big gemm

__device__ inline float lrelu(float x){ return x > 0.f ? x : 0.2f*x; }
__device__ inline unsigned fkey(float x){
  unsigned u = __float_as_uint(x);
  return (u & 0x80000000u) ? ~u : (u | 0x80000000u);
}
__device__ inline float funkey(unsigned k){
  return (k & 0x80000000u) ? __uint_as_float(k & 0x7FFFFFFFu) : __uint_as_float(~k);
}

// ---- edge_index dtype detection (int64 vs int32) ----
__global__ void k_detect(const void* ei, int* flag){
  int t = threadIdx.x;
  int v = ((const int*)ei)[2*t + 1];           // high words if int64
  unsigned long long b = __ballot(v == 0);
  if (t == 0) *flag = (b == ~0ULL) ? 1 : 0;
}

__global__ void k_convert(const void* ei, const int* __restrict__ flag,
                          int* __restrict__ out, int n){
  int i = blockIdx.x*256 + threadIdx.x;
  if (i >= n) return;
  if (*flag) out[i] = (int)(((const long long*)ei)[i]);
  else       out[i] = ((const int*)ei)[i];
}

// ---- generic fp32 tiled GEMM: C[M,N] = A[M,K] @ B[K,N], tiles 64x64, BK=16 ----
__global__ __launch_bounds__(256) void k_gemm(const float* __restrict__ A,
    const float* __restrict__ Bm, float* __restrict__ C, int M, int N, int K){
  __shared__ float As[16][68];
  __shared__ float Bs[16][68];
  int m0 = blockIdx.y*64, n0 = blockIdx.x*64;
  int t = threadIdx.x;
  int tr = t >> 4, tc = t & 15;
  float acc[4][4] = {};
  for (int k0 = 0; k0 < K; k0 += 16){
    int kk = t & 15, mr = t >> 4;
    #pragma unroll
    for (int p = 0; p < 4; p++)
      As[kk][mr + p*16] = A[(size_t)(m0 + mr + p*16)*K + k0 + kk];
    int cc = t & 63, kr = t >> 6;
    #pragma unroll
    for (int p = 0; p < 4; p++)
      Bs[kr + p*4][cc] = Bm[(size_t)(k0 + kr + p*4)*N + n0 + cc];
    __syncthreads();
    #pragma unroll
    for (int k = 0; k < 16; k++){
      float4 av = *(const float4*)&As[k][tr*4];
      float4 bv = *(const float4*)&Bs[k][tc*4];
      float aa[4] = {av.x, av.y, av.z, av.w};
      float bb[4] = {bv.x, bv.y, bv.z, bv.w};
      #pragma unroll
      for (int i = 0; i < 4; i++)
        #pragma unroll
        for (int j = 0; j < 4; j++)
          acc[i][j] = fmaf(aa[i], bb[j], acc[i][j]);
    }
    __syncthreads();
  }
  #pragma unroll
  for (int i = 0; i < 4; i++){
    float4 v = make_float4(acc[i][0], acc[i][1], acc[i][2], acc[i][3]);
    *(float4*)&C[(size_t)(m0 + tr*4 + i)*N + n0 + tc*4] = v;
  }
}

// ---- attention scores a_s[n,h], a_d[n,h] ----
__global__ __launch_bounds__(256) void k_att(const float* __restrict__ hp,
    const float* __restrict__ ws, const float* __restrict__ wd,
    float* __restrict__ a_s, float* __restrict__ a_d){
  int n = blockIdx.x, c = threadIdx.x;
  float h = hp[(size_t)n*HC + c];
  float ps = h * ws[c], pd = h * wd[c];
  #pragma unroll
  for (int o = 32; o; o >>= 1){ ps += __shfl_down(ps, o); pd += __shfl_down(pd, o); }
  if ((c & 63) == 0){ a_s[n*NH + (c>>6)] = ps; a_d[n*NH + (c>>6)] = pd; }
}

__global__ void k_hist(const int* __restrict__ dst, int* counts, int E){
  int i = blockIdx.x*256 + threadIdx.x;
  if (i < E) atomicAdd(&counts[dst[i]], 1);
}

// exclusive scan over counts[0..n) -> offs[0..n], cursor copy. 1 block, 1024 thr.
__global__ __launch_bounds__(1024) void k_scan(const int* __restrict__ counts,
    int* __restrict__ offs, int* __restrict__ cursor, int n){
  __shared__ int sums[1024];
  int t = threadIdx.x;
  const int CHK = 32;
  int base = t * CHK;
  int s = 0;
  for (int i = 0; i < CHK; i++){ int idx = base + i; if (idx < n) s += counts[idx]; }
  sums[t] = s;
  __syncthreads();
  for (int off = 1; off < 1024; off <<= 1){
    int v = (t >= off) ? sums[t - off] : 0;
    __syncthreads();
    sums[t] += v;
    __syncthreads();
  }
  int run = (t == 0) ? 0 : sums[t-1];
  for (int i = 0; i < CHK; i++){
    int idx = base + i;
    if (idx < n){ offs[idx] = run; cursor[idx] = run; run += counts[idx]; }
  }
  if (t == 1023) offs[n] = sums[1023];
}

__global__ void k_copy(const int* __restrict__ a, int* __restrict__ b, int n){
  int i = blockIdx.x*256 + threadIdx.x;
  if (i < n) b[i] = a[i];
}

// segment max over e (incl. virtual self-loops at i in [E, E+NN))
__global__ void k_emax(const int* __restrict__ src, const int* __restrict__ dst,
    const float* __restrict__ a_s, const float* __restrict__ a_d,
    unsigned* __restrict__ m_u, int E){
  int i = blockIdx.x*256 + threadIdx.x;
  int s, d;
  if (i < E){ s = src[i]; d = dst[i]; }
  else if (i < E + NN){ s = d = i - E; }
  else return;
  #pragma unroll
  for (int h = 0; h < NH; h++){
    float e = lrelu(a_s[s*NH + h] + a_d[d*NH + h]);
    atomicMax(&m_u[d*NH + h], fkey(e));
  }
}

// p = exp(e - m[dst]); denom += p; fill CSR (col, pw); self-loop p stored separately
__global__ void k_ep(const int* __restrict__ src, const int* __restrict__ dst,
    const float* __restrict__ a_s, const float* __restrict__ a_d,
    const unsigned* __restrict__ m_u, float* __restrict__ denom,
    float* __restrict__ p_self, int* __restrict__ cursor,
    int* __restrict__ col, float* __restrict__ pw, int E){
  int i = blockIdx.x*256 + threadIdx.x;
  if (i < E){
    int s = src[i], d = dst[i];
    float p[NH];
    #pragma unroll
    for (int h = 0; h < NH; h++){
      float e = lrelu(a_s[s*NH + h] + a_d[d*NH + h]);
      p[h] = expf(e - funkey(m_u[d*NH + h]));
      atomicAdd(&denom[d*NH + h], p[h]);
    }
    int pos = atomicAdd(&cursor[d], 1);
    col[pos] = s;
    *(float4*)&pw[(size_t)pos*4] = make_float4(p[0], p[1], p[2], p[3]);
  } else if (i < E + NN){
    int n = i - E;
    #pragma unroll
    for (int h = 0; h < NH; h++){
      float e = lrelu(a_s[n*NH + h] + a_d[n*NH + h]);
      float p = expf(e - funkey(m_u[n*NH + h]));
      p_self[n*NH + h] = p;
      atomicAdd(&denom[n*NH + h], p);
    }
  }
}

// out[n,c] = relu( (p_self*h[n,c] + sum_e pw[e,h]*h[src_e,c]) / denom[n,h] + bias[c] )
__global__ __launch_bounds__(256) void k_agg(const float* __restrict__ hp,
    const float* __restrict__ pw, const int* __restrict__ col,
    const int* __restrict__ offs, const float* __restrict__ p_self,
    const float* __restrict__ denom, const float* __restrict__ bias,
    float* __restrict__ out){
  int n = blockIdx.x, c = threadIdx.x, h = c >> 6;
  float acc = p_self[n*NH + h] * hp[(size_t)n*HC + c];
  int b0 = offs[n], b1 = offs[n+1];
  for (int i = b0; i < b1; i++){
    int s = col[i];
    acc += pw[(size_t)i*4 + h] * hp[(size_t)s*HC + c];
  }
  out[(size_t)n*HC + c] = fmaxf(acc / denom[n*NH + h] + bias[c], 0.f);
}

__global__ void k_inity(float* __restrict__ y, const float* __restrict__ be){
  int i = blockIdx.x*256 + threadIdx.x;
  if (i < BB*HIDD) y[i] = be[i & (HIDD-1)];
}

// y[64,512] += xg[64, k0:k0+KC] @ We[k0:k0+KC, n0:n0+64]  (split-K, atomic accum)
__global__ __launch_bounds__(256) void k_gemm_big(const float* __restrict__ xg,
    const float* __restrict__ We, float* __restrict__ y){
  __shared__ float As[16][68];
  __shared__ float Bs[16][68];
  int n0 = blockIdx.x*64;
  int k0 = blockIdx.y*KC;
  int t = threadIdx.x, tr = t >> 4, tc = t & 15;
  float acc[4][4] = {};
  for (int kt = 0; kt < KC; kt += 16){
    int kk = t & 15, rr = t >> 4;
    #pragma unroll
    for (int p = 0; p < 4; p++)
      As[kk][rr + p*16] = xg[(size_t)(rr + p*16)*128000 + k0 + kt + kk];
    int cc = t & 63, kr = t >> 6;
    #pragma unroll
    for (int p = 0; p < 4; p++)
      Bs[kr + p*4][cc] = We[(size_t)(k0 + kt + kr + p*4)*HIDD + n0 + cc];
    __syncthreads();
    #pragma unroll
    for (int k = 0; k < 16; k++){
      float4 av = *(const float4*)&As[k][tr*4];
      float4 bv = *(const float4*)&Bs[k][tc*4];
      float aa[4] = {av.x, av.y, av.z, av.w};
      float bb[4] = {bv.x, bv.y, bv.z, bv.w};
      #pragma unroll
      for (int i = 0; i < 4; i++)
        #pragma unroll
        for (int j = 0; j < 4; j++)
          acc[i][j] = fmaf(aa[i], bb[j], acc[i][j]);
    }
    __syncthreads();
  }
  #pragma unroll
  for (int i = 0; i < 4; i++)
    #pragma unroll
    for (int j = 0; j < 4; j++)
      atomicAdd(&y[(tr*4 + i)*HIDD + n0 + tc*4 + j], acc[i][j]);
}

// BatchNorm over batch axis: one block (64 thr = 1 wave) per column
__global__ __launch_bounds__(64) void k_bn(const float* __restrict__ y,
    float* __restrict__ ybn){
  int col = blockIdx.x, r = threadIdx.x;
  float v = y[(size_t)r*HIDD + col];
  float s = v, s2 = v*v;
  #pragma unroll
  for (int o = 32; o; o >>= 1){ s += __shfl_down(s, o); s2 += __shfl_down(s2, o); }
  s = __shfl(s, 0); s2 = __shfl(s2, 0);
  float mean = s * (1.f/BB);
  float var = s2 * (1.f/BB) - mean*mean;
  ybn[(size_t)r*HIDD + col] = (v - mean) * rsqrtf(var + 1e-3f);
}

// LayerNorm over feature axis + relu: block (512 thr) per row
__global__ __launch_bounds__(512) void k_ln(const float* __restrict__ ybn,
    float* __restrict__ yln){
  __shared__ float ssum[8], ssq[8];
  int row = blockIdx.x, t = threadIdx.x;
  float v = ybn[(size_t)row*HIDD + t];
  float s = v, s2 = v*v;
  #pragma unroll
  for (int o = 32; o; o >>= 1){ s += __shfl_down(s, o); s2 += __shfl_down(s2, o); }
  if ((t & 63) == 0){ ssum[t>>6] = s; ssq[t>>6] = s2; }
  __syncthreads();
  if (t == 0){
    float S = 0, S2 = 0;
    for (int i = 0; i < 8; i++){ S += ssum[i]; S2 += ssq[i]; }
    ssum[0] = S; ssq[0] = S2;
  }
  __syncthreads();
  float mean = ssum[0] * (1.f/HIDD);
  float var = ssq[0] * (1.f/HIDD) - mean*mean;
  yln[(size_t)row*HIDD + t] = fmaxf((v - mean) * rsqrtf(var + 1e-5f), 0.f);
}

// z_loc = y@Wmu+bmu ; z_scale = exp(y@Wvar+bvar)+1e-4
__global__ __launch_bounds__(128) void k_heads(const float* __restrict__ yln,
    const float* __restrict__ Wmu, const float* __restrict__ bmu,
    const float* __restrict__ Wvar, const float* __restrict__ bvar,
    float* __restrict__ out){
  __shared__ float yrow[HIDD];
  int b = blockIdx.x, t = threadIdx.x;
  for (int i = t; i < HIDD; i += 128) yrow[i] = yln[(size_t)b*HIDD + i];
  __syncthreads();
  if (t < ZD){
    float acc = bmu[t];
    for (int k = 0; k < HIDD; k++) acc = fmaf(yrow[k], Wmu[(size_t)k*ZD + t], acc);
    out[b*ZD + t] = acc;
  } else {
    int j = t - ZD;
    float acc = bvar[j];
    for (int k = 0; k < HIDD; k++) acc = fmaf(yrow[k], Wvar[(size_t)k*ZD + j], acc);
    out[BB*ZD + b*ZD + j] = expf(acc) + 1e-4f;
  }
}

extern "C" void kernel_launch(void* const* d_in, const int* in_sizes, int n_in,
                              void* d_out, int out_size, void* d_ws, size_t ws_size,
                              hipStream_t stream){
  const float* x    = (const float*)d_in[0];
  const float* W1   = (const float*)d_in[1];
  const float* as1  = (const float*)d_in[2];
  const float* ad1  = (const float*)d_in[3];
  const float* b1   = (const float*)d_in[4];
  const float* W2   = (const float*)d_in[5];
  const float* as2  = (const float*)d_in[6];
  const float* ad2  = (const float*)d_in[7];
  const float* b2   = (const float*)d_in[8];
  const float* We   = (const float*)d_in[9];
  const float* be   = (const float*)d_in[10];
  const float* Wmu  = (const float*)d_in[11];
  const float* bmu  = (const float*)d_in[12];
  const float* Wvar = (const float*)d_in[13];
  const float* bvar = (const float*)d_in[14];
  const void*  ei   = d_in[15];
  int E = in_sizes[15] / 2;

  char* w = (char*)d_ws;
  auto alloc = [&](size_t bytes)->void*{
    void* p = (void*)w; w += (bytes + 255) & ~(size_t)255; return p;
  };
  float*    hp     = (float*)alloc((size_t)NN*HC*4);
  float*    hb     = (float*)alloc((size_t)NN*HC*4);
  float*    a_s    = (float*)alloc((size_t)NN*NH*4);
  float*    a_d    = (float*)alloc((size_t)NN*NH*4);
  unsigned* m_u    = (unsigned*)alloc((size_t)NN*NH*4);
  float*    denom  = (float*)alloc((size_t)NN*NH*4);
  float*    p_self = (float*)alloc((size_t)NN*NH*4);
  int*      counts = (int*)alloc((size_t)NN*4);
  int*      offs   = (int*)alloc((size_t)(NN+1)*4);
  int*      cursor = (int*)alloc((size_t)NN*4);
  int*      col    = (int*)alloc((size_t)E*4);
  float*    pw     = (float*)alloc((size_t)E*16);
  int*      econv  = (int*)alloc((size_t)2*E*4);
  int*      flag   = (int*)alloc(256);
  float*    y      = (float*)alloc((size_t)BB*HIDD*4);
  float*    ybn    = (float*)alloc((size_t)BB*HIDD*4);
  float*    yln    = (float*)alloc((size_t)BB*HIDD*4);

  k_detect<<<1, 64, 0, stream>>>(ei, flag);
  k_convert<<<(2*E + 255)/256, 256, 0, stream>>>(ei, flag, econv, 2*E);
  const int* src  = econv;
  const int* dstp = econv + E;

  int gE = (E + NN + 255) / 256;

  // ---- GAT layer 1 ----
  hipMemsetAsync(counts, 0, (size_t)NN*4, stream);
  hipMemsetAsync(m_u,    0, (size_t)NN*NH*4, stream);
  hipMemsetAsync(denom,  0, (size_t)NN*NH*4, stream);
  k_gemm<<<dim3(HC/64, NN/64), 256, 0, stream>>>(x, W1, hp, NN, HC, FIN);
  k_att<<<NN, 256, 0, stream>>>(hp, as1, ad1, a_s, a_d);
  k_hist<<<(E + 255)/256, 256, 0, stream>>>(dstp, counts, E);
  k_scan<<<1, 1024, 0, stream>>>(counts, offs, cursor, NN);
  k_emax<<<gE, 256, 0, stream>>>(src, dstp, a_s, a_d, m_u, E);
  k_ep<<<gE, 256, 0, stream>>>(src, dstp, a_s, a_d, m_u, denom, p_self, cursor, col, pw, E);
  k_agg<<<NN, 256, 0, stream>>>(hp, pw, col, offs, p_self, denom, b1, hb);

  // ---- GAT layer 2 ----
  k_gemm<<<dim3(HC/64, NN/64), 256, 0, stream>>>(hb, W2, hp, NN, HC, HC);
  k_att<<<NN, 256, 0, stream>>>(hp, as2, ad2, a_s, a_d);
  hipMemsetAsync(m_u,   0, (size_t)NN*NH*4, stream);
  hipMemsetAsync(denom, 0, (size_t)NN*NH*4, stream);
  k_copy<<<(NN + 255)/256, 256, 0, stream>>>(offs, cursor, NN);
  k_emax<<<gE, 256, 0, stream>>>(src, dstp, a_s, a_d, m_u, E);
  k_ep<<<gE, 256, 0, stream>>>(src, dstp, a_s, a_d, m_u, denom, p_self, cursor, col, pw, E);
  k_agg<<<NN, 256, 0, stream>>>(hp, pw, col, offs, p_self, denom, b2, hb);

  // ---- encoder head ----
  k_inity<<<(BB*HIDD + 255)/256, 256, 0, stream>>>(y, be);
  k_gemm_big<<<dim3(HIDD/64, 128000/KC), 256, 0, stream>>>(hb, We, y);
  k_bn<<<HIDD, 64, 0, stream>>>(y, ybn);
  k_ln<<<BB, 512, 0, stream>>>(ybn, yln);
  k_heads<<<BB, 128, 0, stream>>>(yln, Wmu, bmu, Wvar, bvar, (float*)d_out);
}

// Round 2
// 658.133 us; speedup vs baseline: 1.7379x; 1.7379x over previous
//
#include <hip/hip_runtime.h>
#include <math.h>

#define NN 32000
#define FIN 128
#define HC 256      // HEADS*CH
#define NH 4        // heads
#define HIDD 512
#define BB 64       // batch
#define ZD 64
#define KC 512      // k-chunk for big gemm (128000/512 = 250 splits)

__device__ inline float lrelu(float x){ return x > 0.f ? x : 0.2f*x; }

// ---- edge_index dtype detection (int64 vs int32) ----
__global__ void k_detect(const void* ei, int* flag){
  int t = threadIdx.x;
  int v = ((const int*)ei)[2*t + 1];           // high words if int64
  unsigned long long b = __ballot(v == 0);
  if (t == 0) *flag = (b == ~0ULL) ? 1 : 0;
}

__global__ void k_convert(const void* ei, const int* __restrict__ flag,
                          int* __restrict__ out, int n){
  int i = blockIdx.x*256 + threadIdx.x;
  if (i >= n) return;
  if (*flag) out[i] = (int)(((const long long*)ei)[i]);
  else       out[i] = ((const int*)ei)[i];
}

// ---- generic fp32 tiled GEMM: C[M,N] = A[M,K] @ B[K,N], tiles 64x64, BK=16 ----
__global__ __launch_bounds__(256) void k_gemm(const float* __restrict__ A,
    const float* __restrict__ Bm, float* __restrict__ C, int M, int N, int K){
  __shared__ float As[16][68];
  __shared__ float Bs[16][68];
  int m0 = blockIdx.y*64, n0 = blockIdx.x*64;
  int t = threadIdx.x;
  int tr = t >> 4, tc = t & 15;
  float acc[4][4] = {};
  for (int k0 = 0; k0 < K; k0 += 16){
    int kk = t & 15, mr = t >> 4;
    #pragma unroll
    for (int p = 0; p < 4; p++)
      As[kk][mr + p*16] = A[(size_t)(m0 + mr + p*16)*K + k0 + kk];
    int cc = t & 63, kr = t >> 6;
    #pragma unroll
    for (int p = 0; p < 4; p++)
      Bs[kr + p*4][cc] = Bm[(size_t)(k0 + kr + p*4)*N + n0 + cc];
    __syncthreads();
    #pragma unroll
    for (int k = 0; k < 16; k++){
      float4 av = *(const float4*)&As[k][tr*4];
      float4 bv = *(const float4*)&Bs[k][tc*4];
      float aa[4] = {av.x, av.y, av.z, av.w};
      float bb[4] = {bv.x, bv.y, bv.z, bv.w};
      #pragma unroll
      for (int i = 0; i < 4; i++)
        #pragma unroll
        for (int j = 0; j < 4; j++)
          acc[i][j] = fmaf(aa[i], bb[j], acc[i][j]);
    }
    __syncthreads();
  }
  #pragma unroll
  for (int i = 0; i < 4; i++){
    float4 v = make_float4(acc[i][0], acc[i][1], acc[i][2], acc[i][3]);
    *(float4*)&C[(size_t)(m0 + tr*4 + i)*N + n0 + tc*4] = v;
  }
}

// ---- attention scores a_s[n,h], a_d[n,h] ----
__global__ __launch_bounds__(256) void k_att(const float* __restrict__ hp,
    const float* __restrict__ ws, const float* __restrict__ wd,
    float* __restrict__ a_s, float* __restrict__ a_d){
  int n = blockIdx.x, c = threadIdx.x;
  float h = hp[(size_t)n*HC + c];
  float ps = h * ws[c], pd = h * wd[c];
  #pragma unroll
  for (int o = 32; o; o >>= 1){ ps += __shfl_down(ps, o); pd += __shfl_down(pd, o); }
  if ((c & 63) == 0){ a_s[n*NH + (c>>6)] = ps; a_d[n*NH + (c>>6)] = pd; }
}

__global__ void k_hist(const int* __restrict__ dst, int* counts, int E){
  int i = blockIdx.x*256 + threadIdx.x;
  if (i < E) atomicAdd(&counts[dst[i]], 1);
}

// exclusive scan over counts[0..n) -> offs[0..n], cursor copy. 1 block, 1024 thr.
__global__ __launch_bounds__(1024) void k_scan(const int* __restrict__ counts,
    int* __restrict__ offs, int* __restrict__ cursor, int n){
  __shared__ int sums[1024];
  int t = threadIdx.x;
  const int CHK = 32;
  int base = t * CHK;
  int s = 0;
  for (int i = 0; i < CHK; i++){ int idx = base + i; if (idx < n) s += counts[idx]; }
  sums[t] = s;
  __syncthreads();
  for (int off = 1; off < 1024; off <<= 1){
    int v = (t >= off) ? sums[t - off] : 0;
    __syncthreads();
    sums[t] += v;
    __syncthreads();
  }
  int run = (t == 0) ? 0 : sums[t-1];
  for (int i = 0; i < CHK; i++){
    int idx = base + i;
    if (idx < n){ offs[idx] = run; cursor[idx] = run; run += counts[idx]; }
  }
  if (t == 1023) offs[n] = sums[1023];
}

// CSR fill: col[pos] = src  (order within a row is arbitrary; values recomputed later)
__global__ void k_fill(const int* __restrict__ src, const int* __restrict__ dst,
                       int* __restrict__ cursor, int* __restrict__ col, int E){
  int i = blockIdx.x*256 + threadIdx.x;
  if (i < E){
    int pos = atomicAdd(&cursor[dst[i]], 1);
    col[pos] = src[i];
  }
}

// Fused GAT edge phase + aggregation. One block (256 thr = 4 waves) per node.
// Wave h owns head h. Computes segment max, p=exp(e-m), denom, and
// out[n,c] = relu( (p_self*h[n,c] + sum_e p_e*h[src_e,c]) / denom + bias[c] ).
__global__ __launch_bounds__(256) void k_agg(const float* __restrict__ hp,
    const int* __restrict__ col, const int* __restrict__ offs,
    const float* __restrict__ a_s, const float* __restrict__ a_d,
    const float* __restrict__ bias, float* __restrict__ out){
  __shared__ float pe[NH][64];
  __shared__ int   sc[64];
  int n = blockIdx.x, t = threadIdx.x;
  int h = t >> 6, lane = t & 63, c = t;
  int b0 = offs[n], b1 = offs[n+1];
  float adh = a_d[n*NH + h];
  float se  = lrelu(a_s[n*NH + h] + adh);       // self-loop score
  // --- segment max (per head, wave-parallel over edges) ---
  float m = se;
  for (int i = b0 + lane; i < b1; i += 64)
    m = fmaxf(m, lrelu(a_s[col[i]*NH + h] + adh));
  #pragma unroll
  for (int o = 32; o; o >>= 1) m = fmaxf(m, __shfl_xor(m, o));
  float pself = expf(se - m);
  float denp = 0.f;
  float acc = 0.f;
  // --- chunked: compute p into LDS, then gather-aggregate ---
  for (int cb = b0; cb < b1; cb += 64){
    int i = cb + lane;
    float p = 0.f;
    int s = 0;
    if (i < b1){
      s = col[i];
      p = expf(lrelu(a_s[s*NH + h] + adh) - m);
    }
    pe[h][lane] = p;
    denp += p;
    if (h == 0) sc[lane] = s;
    __syncthreads();
    int cnt = min(64, b1 - cb);
    #pragma unroll 4
    for (int j = 0; j < cnt; j++)
      acc = fmaf(pe[h][j], hp[(size_t)sc[j]*HC + c], acc);
    __syncthreads();
  }
  #pragma unroll
  for (int o = 32; o; o >>= 1) denp += __shfl_xor(denp, o);
  float den = denp + pself;
  float hself = hp[(size_t)n*HC + c];
  out[(size_t)n*HC + c] = fmaxf((pself*hself + acc)/den + bias[c], 0.f);
}

__global__ void k_inity(float* __restrict__ y, const float* __restrict__ be){
  int i = blockIdx.x*256 + threadIdx.x;
  if (i < BB*HIDD) y[i] = be[i & (HIDD-1)];
}

// y[64,512] += xg[64, k0:k0+KC] @ We[k0:k0+KC, n0:n0+64]  (split-K, atomic accum)
__global__ __launch_bounds__(256) void k_gemm_big(const float* __restrict__ xg,
    const float* __restrict__ We, float* __restrict__ y){
  __shared__ float As[16][68];
  __shared__ float Bs[16][68];
  int n0 = blockIdx.x*64;
  int k0 = blockIdx.y*KC;
  int t = threadIdx.x, tr = t >> 4, tc = t & 15;
  float acc[4][4] = {};
  for (int kt = 0; kt < KC; kt += 16){
    int kk = t & 15, rr = t >> 4;
    #pragma unroll
    for (int p = 0; p < 4; p++)
      As[kk][rr + p*16] = xg[(size_t)(rr + p*16)*128000 + k0 + kt + kk];
    int cc = t & 63, kr = t >> 6;
    #pragma unroll
    for (int p = 0; p < 4; p++)
      Bs[kr + p*4][cc] = We[(size_t)(k0 + kt + kr + p*4)*HIDD + n0 + cc];
    __syncthreads();
    #pragma unroll
    for (int k = 0; k < 16; k++){
      float4 av = *(const float4*)&As[k][tr*4];
      float4 bv = *(const float4*)&Bs[k][tc*4];
      float aa[4] = {av.x, av.y, av.z, av.w};
      float bb[4] = {bv.x, bv.y, bv.z, bv.w};
      #pragma unroll
      for (int i = 0; i < 4; i++)
        #pragma unroll
        for (int j = 0; j < 4; j++)
          acc[i][j] = fmaf(aa[i], bb[j], acc[i][j]);
    }
    __syncthreads();
  }
  #pragma unroll
  for (int i = 0; i < 4; i++)
    #pragma unroll
    for (int j = 0; j < 4; j++)
      atomicAdd(&y[(tr*4 + i)*HIDD + n0 + tc*4 + j], acc[i][j]);
}

// BatchNorm over batch axis: one block (64 thr = 1 wave) per column
__global__ __launch_bounds__(64) void k_bn(const float* __restrict__ y,
    float* __restrict__ ybn){
  int col = blockIdx.x, r = threadIdx.x;
  float v = y[(size_t)r*HIDD + col];
  float s = v, s2 = v*v;
  #pragma unroll
  for (int o = 32; o; o >>= 1){ s += __shfl_down(s, o); s2 += __shfl_down(s2, o); }
  s = __shfl(s, 0); s2 = __shfl(s2, 0);
  float mean = s * (1.f/BB);
  float var = s2 * (1.f/BB) - mean*mean;
  ybn[(size_t)r*HIDD + col] = (v - mean) * rsqrtf(var + 1e-3f);
}

// LayerNorm over feature axis + relu: block (512 thr) per row
__global__ __launch_bounds__(512) void k_ln(const float* __restrict__ ybn,
    float* __restrict__ yln){
  __shared__ float ssum[8], ssq[8];
  int row = blockIdx.x, t = threadIdx.x;
  float v = ybn[(size_t)row*HIDD + t];
  float s = v, s2 = v*v;
  #pragma unroll
  for (int o = 32; o; o >>= 1){ s += __shfl_down(s, o); s2 += __shfl_down(s2, o); }
  if ((t & 63) == 0){ ssum[t>>6] = s; ssq[t>>6] = s2; }
  __syncthreads();
  if (t == 0){
    float S = 0, S2 = 0;
    for (int i = 0; i < 8; i++){ S += ssum[i]; S2 += ssq[i]; }
    ssum[0] = S; ssq[0] = S2;
  }
  __syncthreads();
  float mean = ssum[0] * (1.f/HIDD);
  float var = ssq[0] * (1.f/HIDD) - mean*mean;
  yln[(size_t)row*HIDD + t] = fmaxf((v - mean) * rsqrtf(var + 1e-5f), 0.f);
}

// z_loc = y@Wmu+bmu ; z_scale = exp(y@Wvar+bvar)+1e-4
__global__ __launch_bounds__(128) void k_heads(const float* __restrict__ yln,
    const float* __restrict__ Wmu, const float* __restrict__ bmu,
    const float* __restrict__ Wvar, const float* __restrict__ bvar,
    float* __restrict__ out){
  __shared__ float yrow[HIDD];
  int b = blockIdx.x, t = threadIdx.x;
  for (int i = t; i < HIDD; i += 128) yrow[i] = yln[(size_t)b*HIDD + i];
  __syncthreads();
  if (t < ZD){
    float acc = bmu[t];
    for (int k = 0; k < HIDD; k++) acc = fmaf(yrow[k], Wmu[(size_t)k*ZD + t], acc);
    out[b*ZD + t] = acc;
  } else {
    int j = t - ZD;
    float acc = bvar[j];
    for (int k = 0; k < HIDD; k++) acc = fmaf(yrow[k], Wvar[(size_t)k*ZD + j], acc);
    out[BB*ZD + b*ZD + j] = expf(acc) + 1e-4f;
  }
}

extern "C" void kernel_launch(void* const* d_in, const int* in_sizes, int n_in,
                              void* d_out, int out_size, void* d_ws, size_t ws_size,
                              hipStream_t stream){
  const float* x    = (const float*)d_in[0];
  const float* W1   = (const float*)d_in[1];
  const float* as1  = (const float*)d_in[2];
  const float* ad1  = (const float*)d_in[3];
  const float* b1   = (const float*)d_in[4];
  const float* W2   = (const float*)d_in[5];
  const float* as2  = (const float*)d_in[6];
  const float* ad2  = (const float*)d_in[7];
  const float* b2   = (const float*)d_in[8];
  const float* We   = (const float*)d_in[9];
  const float* be   = (const float*)d_in[10];
  const float* Wmu  = (const float*)d_in[11];
  const float* bmu  = (const float*)d_in[12];
  const float* Wvar = (const float*)d_in[13];
  const float* bvar = (const float*)d_in[14];
  const void*  ei   = d_in[15];
  int E = in_sizes[15] / 2;

  char* w = (char*)d_ws;
  auto alloc = [&](size_t bytes)->void*{
    void* p = (void*)w; w += (bytes + 255) & ~(size_t)255; return p;
  };
  float*    hp     = (float*)alloc((size_t)NN*HC*4);
  float*    hb     = (float*)alloc((size_t)NN*HC*4);
  float*    a_s    = (float*)alloc((size_t)NN*NH*4);
  float*    a_d    = (float*)alloc((size_t)NN*NH*4);
  int*      counts = (int*)alloc((size_t)NN*4);
  int*      offs   = (int*)alloc((size_t)(NN+1)*4);
  int*      cursor = (int*)alloc((size_t)NN*4);
  int*      col    = (int*)alloc((size_t)E*4);
  int*      econv  = (int*)alloc((size_t)2*E*4);
  int*      flag   = (int*)alloc(256);
  float*    y      = (float*)alloc((size_t)BB*HIDD*4);
  float*    ybn    = (float*)alloc((size_t)BB*HIDD*4);
  float*    yln    = (float*)alloc((size_t)BB*HIDD*4);

  k_detect<<<1, 64, 0, stream>>>(ei, flag);
  k_convert<<<(2*E + 255)/256, 256, 0, stream>>>(ei, flag, econv, 2*E);
  const int* src  = econv;
  const int* dstp = econv + E;

  // ---- CSR build (graph-only; shared by both layers) ----
  hipMemsetAsync(counts, 0, (size_t)NN*4, stream);
  k_hist<<<(E + 255)/256, 256, 0, stream>>>(dstp, counts, E);
  k_scan<<<1, 1024, 0, stream>>>(counts, offs, cursor, NN);
  k_fill<<<(E + 255)/256, 256, 0, stream>>>(src, dstp, cursor, col, E);

  // ---- GAT layer 1 ----
  k_gemm<<<dim3(HC/64, NN/64), 256, 0, stream>>>(x, W1, hp, NN, HC, FIN);
  k_att<<<NN, 256, 0, stream>>>(hp, as1, ad1, a_s, a_d);
  k_agg<<<NN, 256, 0, stream>>>(hp, col, offs, a_s, a_d, b1, hb);

  // ---- GAT layer 2 ----
  k_gemm<<<dim3(HC/64, NN/64), 256, 0, stream>>>(hb, W2, hp, NN, HC, HC);
  k_att<<<NN, 256, 0, stream>>>(hp, as2, ad2, a_s, a_d);
  k_agg<<<NN, 256, 0, stream>>>(hp, col, offs, a_s, a_d, b2, hb);

  // ---- encoder head ----
  k_inity<<<(BB*HIDD + 255)/256, 256, 0, stream>>>(y, be);
  k_gemm_big<<<dim3(HIDD/64, 128000/KC), 256, 0, stream>>>(hb, We, y);
  k_bn<<<HIDD, 64, 0, stream>>>(y, ybn);
  k_ln<<<BB, 512, 0, stream>>>(ybn, yln);
  k_heads<<<BB, 128, 0, stream>>>(yln, Wmu, bmu, Wvar, bvar, (float*)d_out);
}

// Round 3
// 538.264 us; speedup vs baseline: 2.1249x; 1.2227x over previous
//
#include <hip/hip_runtime.h>
#include <math.h>

#define NN 32000
#define FIN 128
#define HC 256      // HEADS*CH
#define NH 4        // heads
#define HIDD 512
#define BB 64       // batch
#define ZD 64
#define NSPLIT 250  // big-gemm K splits
#define KBCH 512    // K rows per split (250*512 = 128000)

typedef __bf16 bf16x8 __attribute__((ext_vector_type(8)));
typedef float f32x4 __attribute__((ext_vector_type(4)));
typedef unsigned int uint;

__device__ inline float lrelu(float x){ return x > 0.f ? x : 0.2f*x; }
__device__ inline unsigned short f2b(float f){           // fp32 -> bf16 RNE
  uint u = __float_as_uint(f);
  return (unsigned short)((u + 0x7FFFu + ((u >> 16) & 1u)) >> 16);
}
__device__ inline float b2f(unsigned short b){ return __uint_as_float(((uint)b) << 16); }

// ---- edge_index dtype detection (int64 vs int32) ----
__global__ void k_detect(const void* ei, int* flag){
  int t = threadIdx.x;
  int v = ((const int*)ei)[2*t + 1];
  unsigned long long b = __ballot(v == 0);
  if (t == 0) *flag = (b == ~0ULL) ? 1 : 0;
}

__global__ void k_convert(const void* ei, const int* __restrict__ flag,
                          int* __restrict__ out, int n){
  int i = blockIdx.x*256 + threadIdx.x;
  if (i >= n) return;
  if (*flag) out[i] = (int)(((const long long*)ei)[i]);
  else       out[i] = ((const int*)ei)[i];
}

// ---- fp32 -> bf16 elementwise ----
__global__ void k_cvt(const float* __restrict__ in, unsigned short* __restrict__ out, int n){
  int i = blockIdx.x*256 + threadIdx.x;
  if (i < n) out[i] = f2b(in[i]);
}

// ---- W [K][256] fp32 -> Wt [256][K] bf16 (transposed for B-frag reads) ----
__global__ void k_cvtT(const float* __restrict__ Wm, unsigned short* __restrict__ Wt, int K){
  int n = blockIdx.x, k = threadIdx.x;
  Wt[n*K + k] = f2b(Wm[k*HC + n]);
}

__global__ void k_hist(const int* __restrict__ dst, int* counts, int E){
  int i = blockIdx.x*256 + threadIdx.x;
  if (i < E) atomicAdd(&counts[dst[i]], 1);
}

__global__ __launch_bounds__(1024) void k_scan(const int* __restrict__ counts,
    int* __restrict__ offs, int* __restrict__ cursor, int n){
  __shared__ int sums[1024];
  int t = threadIdx.x;
  const int CHK = 32;
  int base = t * CHK;
  int s = 0;
  for (int i = 0; i < CHK; i++){ int idx = base + i; if (idx < n) s += counts[idx]; }
  sums[t] = s;
  __syncthreads();
  for (int off = 1; off < 1024; off <<= 1){
    int v = (t >= off) ? sums[t - off] : 0;
    __syncthreads();
    sums[t] += v;
    __syncthreads();
  }
  int run = (t == 0) ? 0 : sums[t-1];
  for (int i = 0; i < CHK; i++){
    int idx = base + i;
    if (idx < n){ offs[idx] = run; cursor[idx] = run; run += counts[idx]; }
  }
  if (t == 1023) offs[n] = sums[1023];
}

__global__ void k_fill(const int* __restrict__ src, const int* __restrict__ dst,
                       int* __restrict__ cursor, int* __restrict__ col, int E){
  int i = blockIdx.x*256 + threadIdx.x;
  if (i < E){
    int pos = atomicAdd(&cursor[dst[i]], 1);
    col[pos] = src[i];
  }
}

// ---- node GEMM (MFMA bf16): out[M,256] = A[M,K] @ Wt^T, fused attention dots ----
// block = 256 thr = 4 waves; BM=64, BN=256(full), BK=32. Wave w owns rows 16w..16w+15.
__global__ __launch_bounds__(256) void k_gemm_n(const unsigned short* __restrict__ A,
    const unsigned short* __restrict__ Wt, int K,
    const float* __restrict__ ws, const float* __restrict__ wd,
    unsigned short* __restrict__ out, float* __restrict__ a_s, float* __restrict__ a_d){
  __shared__ unsigned short As[64][40];   // 80B row stride: 16B-aligned frags, ~2-way banks
  __shared__ unsigned short Bs[256][40];
  int m0 = blockIdx.x * 64;
  int t = threadIdx.x;
  int w = t >> 6, lane = t & 63, l15 = lane & 15, l16 = lane >> 4;
  f32x4 acc[16];
  #pragma unroll
  for (int c = 0; c < 16; c++) acc[c] = (f32x4){0.f,0.f,0.f,0.f};

  for (int k0 = 0; k0 < K; k0 += 32){
    { // stage A: [64 rows][32 k] bf16
      int row = t >> 2, ko = (t & 3) * 8;
      *(uint4*)&As[row][ko] = *(const uint4*)&A[(size_t)(m0 + row)*K + k0 + ko];
    }
    { // stage B: [256 cols][32 k] bf16 (Wt already [n][k])
      #pragma unroll
      for (int p = 0; p < 4; p++)
        *(uint4*)&Bs[t][p*8] = *(const uint4*)&Wt[(size_t)t*K + k0 + p*8];
    }
    __syncthreads();
    bf16x8 af = *(const bf16x8*)&As[w*16 + l15][l16*8];
    #pragma unroll
    for (int c = 0; c < 16; c++){
      bf16x8 bfr = *(const bf16x8*)&Bs[c*16 + l15][l16*8];
      acc[c] = __builtin_amdgcn_mfma_f32_16x16x32_bf16(af, bfr, acc[c], 0, 0, 0);
    }
    __syncthreads();
  }

  // epilogue: store bf16 h, and per-head dots a_s = h·att_src, a_d = h·att_dst
  #pragma unroll
  for (int r = 0; r < 4; r++){
    int row = m0 + w*16 + l16*4 + r;
    float hs[NH] = {0,0,0,0}, hd[NH] = {0,0,0,0};
    #pragma unroll
    for (int c = 0; c < 16; c++){
      float v = acc[c][r];
      int colc = c*16 + l15;
      out[(size_t)row*HC + colc] = f2b(v);
      hs[c>>2] += v * ws[colc];
      hd[c>>2] += v * wd[colc];
    }
    #pragma unroll
    for (int h = 0; h < NH; h++){
      float s = hs[h], d = hd[h];
      #pragma unroll
      for (int o = 1; o < 16; o <<= 1){ s += __shfl_xor(s, o); d += __shfl_xor(d, o); }
      if (l15 == h){ a_s[row*NH + h] = s; a_d[row*NH + h] = d; }
    }
  }
}

// ---- fused GAT edge phase + aggregation (bf16 h) ----
__global__ __launch_bounds__(256) void k_agg(const unsigned short* __restrict__ hp,
    const int* __restrict__ col, const int* __restrict__ offs,
    const float* __restrict__ a_s, const float* __restrict__ a_d,
    const float* __restrict__ bias, unsigned short* __restrict__ outb){
  __shared__ float pe[NH][64];
  __shared__ int   sc[64];
  int n = blockIdx.x, t = threadIdx.x;
  int h = t >> 6, lane = t & 63, c = t;
  int b0 = offs[n], b1 = offs[n+1];
  float adh = a_d[n*NH + h];
  float se  = lrelu(a_s[n*NH + h] + adh);
  float m = se;
  for (int i = b0 + lane; i < b1; i += 64)
    m = fmaxf(m, lrelu(a_s[col[i]*NH + h] + adh));
  #pragma unroll
  for (int o = 32; o; o >>= 1) m = fmaxf(m, __shfl_xor(m, o));
  float pself = expf(se - m);
  float denp = 0.f;
  float acc = 0.f;
  for (int cb = b0; cb < b1; cb += 64){
    int i = cb + lane;
    float p = 0.f;
    int s = 0;
    if (i < b1){
      s = col[i];
      p = expf(lrelu(a_s[s*NH + h] + adh) - m);
    }
    pe[h][lane] = p;
    denp += p;
    if (h == 0) sc[lane] = s;
    __syncthreads();
    int cnt = min(64, b1 - cb);
    #pragma unroll 4
    for (int j = 0; j < cnt; j++)
      acc = fmaf(pe[h][j], b2f(hp[(size_t)sc[j]*HC + c]), acc);
    __syncthreads();
  }
  #pragma unroll
  for (int o = 32; o; o >>= 1) denp += __shfl_xor(denp, o);
  float den = denp + pself;
  float hself = b2f(hp[(size_t)n*HC + c]);
  outb[(size_t)n*HC + c] = f2b(fmaxf((pself*hself + acc)/den + bias[c], 0.f));
}

// ---- big GEMM (MFMA bf16): part[kc] = xg[:, kchunk] @ We[kchunk, n-group] ----
// grid (2 n-groups, 250 k-chunks); block 256 thr; wave w owns rows 16w..16w+15 x 256 cols.
__global__ __launch_bounds__(256) void k_gemm_big(const unsigned short* __restrict__ xg,
    const float* __restrict__ We, float* __restrict__ part){
  __shared__ unsigned short As[64][40];
  __shared__ unsigned short Bs[256][40];
  int n0 = blockIdx.x * 256;
  int kc = blockIdx.y;
  int kbase = kc * KBCH;
  int t = threadIdx.x, w = t >> 6, lane = t & 63, l15 = lane & 15, l16 = lane >> 4;
  f32x4 acc[16];
  #pragma unroll
  for (int c = 0; c < 16; c++) acc[c] = (f32x4){0.f,0.f,0.f,0.f};

  for (int ks = 0; ks < KBCH; ks += 32){
    int k0 = kbase + ks;
    { // stage A (xg is bf16 [64][128000])
      int row = t >> 2, ko = (t & 3) * 8;
      *(uint4*)&As[row][ko] = *(const uint4*)&xg[(size_t)row*128000 + k0 + ko];
    }
    // stage B: transpose-convert We fp32 [32 k][256 cols] -> Bs [col][k] bf16
    #pragma unroll
    for (int rep = 0; rep < 16; rep++){
      int cc = (t & 63) + 64*(rep & 3);
      int kp = (t >> 6) + 4*(rep >> 2);
      float v0 = We[(size_t)(k0 + 2*kp    )*HIDD + n0 + cc];
      float v1 = We[(size_t)(k0 + 2*kp + 1)*HIDD + n0 + cc];
      uint pk = ((uint)f2b(v1) << 16) | (uint)f2b(v0);
      *(uint*)&Bs[cc][kp*2] = pk;
    }
    __syncthreads();
    bf16x8 af = *(const bf16x8*)&As[w*16 + l15][l16*8];
    #pragma unroll
    for (int c = 0; c < 16; c++){
      bf16x8 bfr = *(const bf16x8*)&Bs[c*16 + l15][l16*8];
      acc[c] = __builtin_amdgcn_mfma_f32_16x16x32_bf16(af, bfr, acc[c], 0, 0, 0);
    }
    __syncthreads();
  }
  float* pbase = part + (size_t)kc*BB*HIDD;
  #pragma unroll
  for (int r = 0; r < 4; r++){
    int row = w*16 + l16*4 + r;
    #pragma unroll
    for (int c = 0; c < 16; c++)
      pbase[row*HIDD + n0 + c*16 + l15] = acc[c][r];
  }
}

// ---- reduce partials + bias ----
__global__ void k_reduce(const float* __restrict__ part, const float* __restrict__ be,
                         float* __restrict__ y){
  int o = blockIdx.x*256 + threadIdx.x;
  float s = 0.f;
  #pragma unroll 5
  for (int k = 0; k < NSPLIT; k++) s += part[(size_t)k*BB*HIDD + o];
  y[o] = s + be[o & (HIDD-1)];
}

// BatchNorm over batch axis
__global__ __launch_bounds__(64) void k_bn(const float* __restrict__ y,
    float* __restrict__ ybn){
  int colb = blockIdx.x, r = threadIdx.x;
  float v = y[(size_t)r*HIDD + colb];
  float s = v, s2 = v*v;
  #pragma unroll
  for (int o = 32; o; o >>= 1){ s += __shfl_down(s, o); s2 += __shfl_down(s2, o); }
  s = __shfl(s, 0); s2 = __shfl(s2, 0);
  float mean = s * (1.f/BB);
  float var = s2 * (1.f/BB) - mean*mean;
  ybn[(size_t)r*HIDD + colb] = (v - mean) * rsqrtf(var + 1e-3f);
}

// LayerNorm + relu
__global__ __launch_bounds__(512) void k_ln(const float* __restrict__ ybn,
    float* __restrict__ yln){
  __shared__ float ssum[8], ssq[8];
  int row = blockIdx.x, t = threadIdx.x;
  float v = ybn[(size_t)row*HIDD + t];
  float s = v, s2 = v*v;
  #pragma unroll
  for (int o = 32; o; o >>= 1){ s += __shfl_down(s, o); s2 += __shfl_down(s2, o); }
  if ((t & 63) == 0){ ssum[t>>6] = s; ssq[t>>6] = s2; }
  __syncthreads();
  if (t == 0){
    float S = 0, S2 = 0;
    for (int i = 0; i < 8; i++){ S += ssum[i]; S2 += ssq[i]; }
    ssum[0] = S; ssq[0] = S2;
  }
  __syncthreads();
  float mean = ssum[0] * (1.f/HIDD);
  float var = ssq[0] * (1.f/HIDD) - mean*mean;
  yln[(size_t)row*HIDD + t] = fmaxf((v - mean) * rsqrtf(var + 1e-5f), 0.f);
}

__global__ __launch_bounds__(128) void k_heads(const float* __restrict__ yln,
    const float* __restrict__ Wmu, const float* __restrict__ bmu,
    const float* __restrict__ Wvar, const float* __restrict__ bvar,
    float* __restrict__ out){
  __shared__ float yrow[HIDD];
  int b = blockIdx.x, t = threadIdx.x;
  for (int i = t; i < HIDD; i += 128) yrow[i] = yln[(size_t)b*HIDD + i];
  __syncthreads();
  if (t < ZD){
    float acc = bmu[t];
    for (int k = 0; k < HIDD; k++) acc = fmaf(yrow[k], Wmu[(size_t)k*ZD + t], acc);
    out[b*ZD + t] = acc;
  } else {
    int j = t - ZD;
    float acc = bvar[j];
    for (int k = 0; k < HIDD; k++) acc = fmaf(yrow[k], Wvar[(size_t)k*ZD + j], acc);
    out[BB*ZD + b*ZD + j] = expf(acc) + 1e-4f;
  }
}

extern "C" void kernel_launch(void* const* d_in, const int* in_sizes, int n_in,
                              void* d_out, int out_size, void* d_ws, size_t ws_size,
                              hipStream_t stream){
  const float* x    = (const float*)d_in[0];
  const float* W1   = (const float*)d_in[1];
  const float* as1  = (const float*)d_in[2];
  const float* ad1  = (const float*)d_in[3];
  const float* b1   = (const float*)d_in[4];
  const float* W2   = (const float*)d_in[5];
  const float* as2  = (const float*)d_in[6];
  const float* ad2  = (const float*)d_in[7];
  const float* b2   = (const float*)d_in[8];
  const float* We   = (const float*)d_in[9];
  const float* be   = (const float*)d_in[10];
  const float* Wmu  = (const float*)d_in[11];
  const float* bmu  = (const float*)d_in[12];
  const float* Wvar = (const float*)d_in[13];
  const float* bvar = (const float*)d_in[14];
  const void*  ei   = d_in[15];
  int E = in_sizes[15] / 2;

  char* w = (char*)d_ws;
  auto alloc = [&](size_t bytes)->void*{
    void* p = (void*)w; w += (bytes + 255) & ~(size_t)255; return p;
  };
  unsigned short* gb   = (unsigned short*)alloc((size_t)NN*HC*2);  // gemm out (both layers)
  unsigned short* ab   = (unsigned short*)alloc((size_t)NN*HC*2);  // agg out (both layers; layer2 = xg)
  unsigned short* xb   = (unsigned short*)alloc((size_t)NN*FIN*2);
  unsigned short* Wt1  = (unsigned short*)alloc((size_t)HC*FIN*2);
  unsigned short* Wt2  = (unsigned short*)alloc((size_t)HC*HC*2);
  float*    a_s    = (float*)alloc((size_t)NN*NH*4);
  float*    a_d    = (float*)alloc((size_t)NN*NH*4);
  int*      counts = (int*)alloc((size_t)NN*4);
  int*      offs   = (int*)alloc((size_t)(NN+1)*4);
  int*      cursor = (int*)alloc((size_t)NN*4);
  int*      col    = (int*)alloc((size_t)E*4);
  int*      econv  = (int*)alloc((size_t)2*E*4);
  int*      flag   = (int*)alloc(256);
  float*    part   = (float*)alloc((size_t)NSPLIT*BB*HIDD*4);
  float*    y      = (float*)alloc((size_t)BB*HIDD*4);
  float*    ybn    = (float*)alloc((size_t)BB*HIDD*4);
  float*    yln    = (float*)alloc((size_t)BB*HIDD*4);

  k_detect<<<1, 64, 0, stream>>>(ei, flag);
  k_convert<<<(2*E + 255)/256, 256, 0, stream>>>(ei, flag, econv, 2*E);
  const int* src  = econv;
  const int* dstp = econv + E;

  // CSR (graph-only; shared by both layers)
  hipMemsetAsync(counts, 0, (size_t)NN*4, stream);
  k_hist<<<(E + 255)/256, 256, 0, stream>>>(dstp, counts, E);
  k_scan<<<1, 1024, 0, stream>>>(counts, offs, cursor, NN);
  k_fill<<<(E + 255)/256, 256, 0, stream>>>(src, dstp, cursor, col, E);

  // bf16 conversions
  k_cvt<<<(NN*FIN + 255)/256, 256, 0, stream>>>(x, xb, NN*FIN);
  k_cvtT<<<HC, FIN, 0, stream>>>(W1, Wt1, FIN);
  k_cvtT<<<HC, HC,  0, stream>>>(W2, Wt2, HC);

  // GAT layer 1
  k_gemm_n<<<NN/64, 256, 0, stream>>>(xb, Wt1, FIN, as1, ad1, gb, a_s, a_d);
  k_agg<<<NN, 256, 0, stream>>>(gb, col, offs, a_s, a_d, b1, ab);

  // GAT layer 2
  k_gemm_n<<<NN/64, 256, 0, stream>>>(ab, Wt2, HC, as2, ad2, gb, a_s, a_d);
  k_agg<<<NN, 256, 0, stream>>>(gb, col, offs, a_s, a_d, b2, ab);  // ab = xg (bf16)

  // encoder head
  k_gemm_big<<<dim3(2, NSPLIT), 256, 0, stream>>>(ab, We, part);
  k_reduce<<<BB*HIDD/256, 256, 0, stream>>>(part, be, y);
  k_bn<<<HIDD, 64, 0, stream>>>(y, ybn);
  k_ln<<<BB, 512, 0, stream>>>(ybn, yln);
  k_heads<<<BB, 128, 0, stream>>>(yln, Wmu, bmu, Wvar, bvar, (float*)d_out);
}

// Round 4
// 447.507 us; speedup vs baseline: 2.5559x; 1.2028x over previous
//
#include <hip/hip_runtime.h>
#include <math.h>

#define NN 32000
#define FIN 128
#define HC 256      // HEADS*CH
#define NH 4        // heads
#define HIDD 512
#define BB 64       // batch
#define ZD 64
#define NSPLIT 250  // big-gemm K splits
#define KBCH 512    // K rows per split (250*512 = 128000)
#define BNB 128     // big-gemm N per block (4 n-groups)

typedef __bf16 bf16x8 __attribute__((ext_vector_type(8)));
typedef float f32x4 __attribute__((ext_vector_type(4)));
typedef unsigned int uint;

__device__ inline float lrelu(float x){ return x > 0.f ? x : 0.2f*x; }
__device__ inline unsigned short f2b(float f){           // fp32 -> bf16 RNE
  uint u = __float_as_uint(f);
  return (unsigned short)((u + 0x7FFFu + ((u >> 16) & 1u)) >> 16);
}
__device__ inline float b2f(unsigned short b){ return __uint_as_float(((uint)b) << 16); }

// ---- edge_index dtype detection (int64 vs int32) ----
__global__ void k_detect(const void* ei, int* flag){
  int t = threadIdx.x;
  int v = ((const int*)ei)[2*t + 1];
  unsigned long long b = __ballot(v == 0);
  if (t == 0) *flag = (b == ~0ULL) ? 1 : 0;
}

__global__ void k_convert(const void* ei, const int* __restrict__ flag,
                          int* __restrict__ out, int n){
  int i = blockIdx.x*256 + threadIdx.x;
  if (i >= n) return;
  if (*flag) out[i] = (int)(((const long long*)ei)[i]);
  else       out[i] = ((const int*)ei)[i];
}

// ---- fp32 -> bf16 elementwise ----
__global__ void k_cvt(const float* __restrict__ in, unsigned short* __restrict__ out, int n){
  int i = blockIdx.x*256 + threadIdx.x;
  if (i < n) out[i] = f2b(in[i]);
}

// ---- W [K][256] fp32 -> Wt [256][K] bf16 (transposed for B-frag reads) ----
__global__ void k_cvtT(const float* __restrict__ Wm, unsigned short* __restrict__ Wt, int K){
  int n = blockIdx.x, k = threadIdx.x;
  Wt[n*K + k] = f2b(Wm[k*HC + n]);
}

__global__ void k_hist(const int* __restrict__ dst, int* counts, int E){
  int i = blockIdx.x*256 + threadIdx.x;
  if (i < E) atomicAdd(&counts[dst[i]], 1);
}

__global__ __launch_bounds__(1024) void k_scan(const int* __restrict__ counts,
    int* __restrict__ offs, int* __restrict__ cursor, int n){
  __shared__ int sums[1024];
  int t = threadIdx.x;
  const int CHK = 32;
  int base = t * CHK;
  int s = 0;
  for (int i = 0; i < CHK; i++){ int idx = base + i; if (idx < n) s += counts[idx]; }
  sums[t] = s;
  __syncthreads();
  for (int off = 1; off < 1024; off <<= 1){
    int v = (t >= off) ? sums[t - off] : 0;
    __syncthreads();
    sums[t] += v;
    __syncthreads();
  }
  int run = (t == 0) ? 0 : sums[t-1];
  for (int i = 0; i < CHK; i++){
    int idx = base + i;
    if (idx < n){ offs[idx] = run; cursor[idx] = run; run += counts[idx]; }
  }
  if (t == 1023) offs[n] = sums[1023];
}

__global__ void k_fill(const int* __restrict__ src, const int* __restrict__ dst,
                       int* __restrict__ cursor, int* __restrict__ col, int E){
  int i = blockIdx.x*256 + threadIdx.x;
  if (i < E){
    int pos = atomicAdd(&cursor[dst[i]], 1);
    col[pos] = src[i];
  }
}

// ---- node GEMM (MFMA bf16): out[M,256] = A[M,K] @ Wt^T, fused attention dots ----
__global__ __launch_bounds__(256) void k_gemm_n(const unsigned short* __restrict__ A,
    const unsigned short* __restrict__ Wt, int K,
    const float* __restrict__ ws, const float* __restrict__ wd,
    unsigned short* __restrict__ out, float* __restrict__ a_s, float* __restrict__ a_d){
  __shared__ unsigned short As[64][40];
  __shared__ unsigned short Bs[256][40];
  int m0 = blockIdx.x * 64;
  int t = threadIdx.x;
  int w = t >> 6, lane = t & 63, l15 = lane & 15, l16 = lane >> 4;
  f32x4 acc[16];
  #pragma unroll
  for (int c = 0; c < 16; c++) acc[c] = (f32x4){0.f,0.f,0.f,0.f};

  for (int k0 = 0; k0 < K; k0 += 32){
    { // stage A: [64 rows][32 k] bf16
      int row = t >> 2, ko = (t & 3) * 8;
      *(uint4*)&As[row][ko] = *(const uint4*)&A[(size_t)(m0 + row)*K + k0 + ko];
    }
    { // stage B: [256 cols][32 k] bf16 (Wt already [n][k])
      #pragma unroll
      for (int p = 0; p < 4; p++)
        *(uint4*)&Bs[t][p*8] = *(const uint4*)&Wt[(size_t)t*K + k0 + p*8];
    }
    __syncthreads();
    bf16x8 af = *(const bf16x8*)&As[w*16 + l15][l16*8];
    #pragma unroll
    for (int c = 0; c < 16; c++){
      bf16x8 bfr = *(const bf16x8*)&Bs[c*16 + l15][l16*8];
      acc[c] = __builtin_amdgcn_mfma_f32_16x16x32_bf16(af, bfr, acc[c], 0, 0, 0);
    }
    __syncthreads();
  }

  // epilogue: store bf16 h, and per-head dots a_s = h·att_src, a_d = h·att_dst
  #pragma unroll
  for (int r = 0; r < 4; r++){
    int row = m0 + w*16 + l16*4 + r;
    float hs[NH] = {0,0,0,0}, hd[NH] = {0,0,0,0};
    #pragma unroll
    for (int c = 0; c < 16; c++){
      float v = acc[c][r];
      int colc = c*16 + l15;
      out[(size_t)row*HC + colc] = f2b(v);
      hs[c>>2] += v * ws[colc];
      hd[c>>2] += v * wd[colc];
    }
    #pragma unroll
    for (int h = 0; h < NH; h++){
      float s = hs[h], d = hd[h];
      #pragma unroll
      for (int o = 1; o < 16; o <<= 1){ s += __shfl_xor(s, o); d += __shfl_xor(d, o); }
      if (l15 == h){ a_s[row*NH + h] = s; a_d[row*NH + h] = d; }
    }
  }
}

// ---- fused GAT edge phase + aggregation (bf16 h) ----
__global__ __launch_bounds__(256) void k_agg(const unsigned short* __restrict__ hp,
    const int* __restrict__ col, const int* __restrict__ offs,
    const float* __restrict__ a_s, const float* __restrict__ a_d,
    const float* __restrict__ bias, unsigned short* __restrict__ outb){
  __shared__ float pe[NH][64];
  __shared__ int   sc[64];
  int n = blockIdx.x, t = threadIdx.x;
  int h = t >> 6, lane = t & 63, c = t;
  int b0 = offs[n], b1 = offs[n+1];
  float adh = a_d[n*NH + h];
  float se  = lrelu(a_s[n*NH + h] + adh);
  float m = se;
  for (int i = b0 + lane; i < b1; i += 64)
    m = fmaxf(m, lrelu(a_s[col[i]*NH + h] + adh));
  #pragma unroll
  for (int o = 32; o; o >>= 1) m = fmaxf(m, __shfl_xor(m, o));
  float pself = expf(se - m);
  float denp = 0.f;
  float acc = 0.f;
  for (int cb = b0; cb < b1; cb += 64){
    int i = cb + lane;
    float p = 0.f;
    int s = 0;
    if (i < b1){
      s = col[i];
      p = expf(lrelu(a_s[s*NH + h] + adh) - m);
    }
    pe[h][lane] = p;
    denp += p;
    if (h == 0) sc[lane] = s;
    __syncthreads();
    int cnt = min(64, b1 - cb);
    #pragma unroll 4
    for (int j = 0; j < cnt; j++)
      acc = fmaf(pe[h][j], b2f(hp[(size_t)sc[j]*HC + c]), acc);
    __syncthreads();
  }
  #pragma unroll
  for (int o = 32; o; o >>= 1) denp += __shfl_xor(denp, o);
  float den = denp + pself;
  float hself = b2f(hp[(size_t)n*HC + c]);
  outb[(size_t)n*HC + c] = f2b(fmaxf((pself*hself + acc)/den + bias[c], 0.f));
}

// ---- big GEMM (MFMA bf16): part[kc] += xg[:, kchunk] @ We[kchunk, n-block] ----
// grid (4 n-blocks of 128, 250 k-chunks); block 256 thr = 4 waves.
// B-staging: two-phase (16 loads into regs BEFORE barrier, pack+write after)
// to avoid per-rep waitcnt serialization (round-3 bug: 14K cyc/K-step).
__global__ __launch_bounds__(256) void k_gemm_big(const unsigned short* __restrict__ xg,
    const float* __restrict__ We, float* __restrict__ part){
  __shared__ unsigned short As[64][40];
  __shared__ unsigned short Bs[BNB][40];
  int n0 = blockIdx.x * BNB;
  int kc = blockIdx.y;
  int kbase = kc * KBCH;
  int t = threadIdx.x, w = t >> 6, lane = t & 63, l15 = lane & 15, l16 = lane >> 4;
  int cc = t & (BNB-1);          // column this thread stages
  int khalf = t >> 7;            // 0: k 0..15, 1: k 16..31
  int arow = t >> 2, ako = (t & 3) * 8;
  f32x4 acc[8];
  #pragma unroll
  for (int c = 0; c < 8; c++) acc[c] = (f32x4){0.f,0.f,0.f,0.f};

  for (int ks = 0; ks < KBCH; ks += 32){
    int k0 = kbase + ks;
    // ---- phase 1: issue ALL global loads (before barrier -> overlap prev MFMA)
    float rv[16];
    const float* bp = We + (size_t)(k0 + khalf*16)*HIDD + n0 + cc;
    #pragma unroll
    for (int m = 0; m < 16; m++) rv[m] = bp[(size_t)m*HIDD];
    uint4 a4 = *(const uint4*)&xg[(size_t)arow*128000 + k0 + ako];
    __syncthreads();   // previous iteration's LDS reads complete
    // ---- phase 2: pack + write (single waitcnt for all loads)
    *(uint4*)&As[arow][ako] = a4;
    #pragma unroll
    for (int j = 0; j < 8; j++){
      uint pk = ((uint)f2b(rv[2*j+1]) << 16) | (uint)f2b(rv[2*j]);
      *(uint*)&Bs[cc][khalf*16 + 2*j] = pk;
    }
    __syncthreads();
    // ---- MFMA phase
    bf16x8 af = *(const bf16x8*)&As[w*16 + l15][l16*8];
    #pragma unroll
    for (int c = 0; c < 8; c++){
      bf16x8 bfr = *(const bf16x8*)&Bs[c*16 + l15][l16*8];
      acc[c] = __builtin_amdgcn_mfma_f32_16x16x32_bf16(af, bfr, acc[c], 0, 0, 0);
    }
  }
  float* pbase = part + (size_t)kc*BB*HIDD;
  #pragma unroll
  for (int r = 0; r < 4; r++){
    int row = w*16 + l16*4 + r;
    #pragma unroll
    for (int c = 0; c < 8; c++)
      pbase[row*HIDD + n0 + c*16 + l15] = acc[c][r];
  }
}

// ---- reduce partials + bias ----
__global__ void k_reduce(const float* __restrict__ part, const float* __restrict__ be,
                         float* __restrict__ y){
  int o = blockIdx.x*256 + threadIdx.x;
  float s = 0.f;
  #pragma unroll 5
  for (int k = 0; k < NSPLIT; k++) s += part[(size_t)k*BB*HIDD + o];
  y[o] = s + be[o & (HIDD-1)];
}

// BatchNorm over batch axis
__global__ __launch_bounds__(64) void k_bn(const float* __restrict__ y,
    float* __restrict__ ybn){
  int colb = blockIdx.x, r = threadIdx.x;
  float v = y[(size_t)r*HIDD + colb];
  float s = v, s2 = v*v;
  #pragma unroll
  for (int o = 32; o; o >>= 1){ s += __shfl_down(s, o); s2 += __shfl_down(s2, o); }
  s = __shfl(s, 0); s2 = __shfl(s2, 0);
  float mean = s * (1.f/BB);
  float var = s2 * (1.f/BB) - mean*mean;
  ybn[(size_t)r*HIDD + colb] = (v - mean) * rsqrtf(var + 1e-3f);
}

// LayerNorm + relu
__global__ __launch_bounds__(512) void k_ln(const float* __restrict__ ybn,
    float* __restrict__ yln){
  __shared__ float ssum[8], ssq[8];
  int row = blockIdx.x, t = threadIdx.x;
  float v = ybn[(size_t)row*HIDD + t];
  float s = v, s2 = v*v;
  #pragma unroll
  for (int o = 32; o; o >>= 1){ s += __shfl_down(s, o); s2 += __shfl_down(s2, o); }
  if ((t & 63) == 0){ ssum[t>>6] = s; ssq[t>>6] = s2; }
  __syncthreads();
  if (t == 0){
    float S = 0, S2 = 0;
    for (int i = 0; i < 8; i++){ S += ssum[i]; S2 += ssq[i]; }
    ssum[0] = S; ssq[0] = S2;
  }
  __syncthreads();
  float mean = ssum[0] * (1.f/HIDD);
  float var = ssq[0] * (1.f/HIDD) - mean*mean;
  yln[(size_t)row*HIDD + t] = fmaxf((v - mean) * rsqrtf(var + 1e-5f), 0.f);
}

__global__ __launch_bounds__(128) void k_heads(const float* __restrict__ yln,
    const float* __restrict__ Wmu, const float* __restrict__ bmu,
    const float* __restrict__ Wvar, const float* __restrict__ bvar,
    float* __restrict__ out){
  __shared__ float yrow[HIDD];
  int b = blockIdx.x, t = threadIdx.x;
  for (int i = t; i < HIDD; i += 128) yrow[i] = yln[(size_t)b*HIDD + i];
  __syncthreads();
  if (t < ZD){
    float acc = bmu[t];
    for (int k = 0; k < HIDD; k++) acc = fmaf(yrow[k], Wmu[(size_t)k*ZD + t], acc);
    out[b*ZD + t] = acc;
  } else {
    int j = t - ZD;
    float acc = bvar[j];
    for (int k = 0; k < HIDD; k++) acc = fmaf(yrow[k], Wvar[(size_t)k*ZD + j], acc);
    out[BB*ZD + b*ZD + j] = expf(acc) + 1e-4f;
  }
}

extern "C" void kernel_launch(void* const* d_in, const int* in_sizes, int n_in,
                              void* d_out, int out_size, void* d_ws, size_t ws_size,
                              hipStream_t stream){
  const float* x    = (const float*)d_in[0];
  const float* W1   = (const float*)d_in[1];
  const float* as1  = (const float*)d_in[2];
  const float* ad1  = (const float*)d_in[3];
  const float* b1   = (const float*)d_in[4];
  const float* W2   = (const float*)d_in[5];
  const float* as2  = (const float*)d_in[6];
  const float* ad2  = (const float*)d_in[7];
  const float* b2   = (const float*)d_in[8];
  const float* We   = (const float*)d_in[9];
  const float* be   = (const float*)d_in[10];
  const float* Wmu  = (const float*)d_in[11];
  const float* bmu  = (const float*)d_in[12];
  const float* Wvar = (const float*)d_in[13];
  const float* bvar = (const float*)d_in[14];
  const void*  ei   = d_in[15];
  int E = in_sizes[15] / 2;

  char* w = (char*)d_ws;
  auto alloc = [&](size_t bytes)->void*{
    void* p = (void*)w; w += (bytes + 255) & ~(size_t)255; return p;
  };
  unsigned short* gb   = (unsigned short*)alloc((size_t)NN*HC*2);
  unsigned short* ab   = (unsigned short*)alloc((size_t)NN*HC*2);
  unsigned short* xb   = (unsigned short*)alloc((size_t)NN*FIN*2);
  unsigned short* Wt1  = (unsigned short*)alloc((size_t)HC*FIN*2);
  unsigned short* Wt2  = (unsigned short*)alloc((size_t)HC*HC*2);
  float*    a_s    = (float*)alloc((size_t)NN*NH*4);
  float*    a_d    = (float*)alloc((size_t)NN*NH*4);
  int*      counts = (int*)alloc((size_t)NN*4);
  int*      offs   = (int*)alloc((size_t)(NN+1)*4);
  int*      cursor = (int*)alloc((size_t)NN*4);
  int*      col    = (int*)alloc((size_t)E*4);
  int*      econv  = (int*)alloc((size_t)2*E*4);
  int*      flag   = (int*)alloc(256);
  float*    part   = (float*)alloc((size_t)NSPLIT*BB*HIDD*4);
  float*    y      = (float*)alloc((size_t)BB*HIDD*4);
  float*    ybn    = (float*)alloc((size_t)BB*HIDD*4);
  float*    yln    = (float*)alloc((size_t)BB*HIDD*4);

  k_detect<<<1, 64, 0, stream>>>(ei, flag);
  k_convert<<<(2*E + 255)/256, 256, 0, stream>>>(ei, flag, econv, 2*E);
  const int* src  = econv;
  const int* dstp = econv + E;

  // CSR (graph-only; shared by both layers)
  hipMemsetAsync(counts, 0, (size_t)NN*4, stream);
  k_hist<<<(E + 255)/256, 256, 0, stream>>>(dstp, counts, E);
  k_scan<<<1, 1024, 0, stream>>>(counts, offs, cursor, NN);
  k_fill<<<(E + 255)/256, 256, 0, stream>>>(src, dstp, cursor, col, E);

  // bf16 conversions
  k_cvt<<<(NN*FIN + 255)/256, 256, 0, stream>>>(x, xb, NN*FIN);
  k_cvtT<<<HC, FIN, 0, stream>>>(W1, Wt1, FIN);
  k_cvtT<<<HC, HC,  0, stream>>>(W2, Wt2, HC);

  // GAT layer 1
  k_gemm_n<<<NN/64, 256, 0, stream>>>(xb, Wt1, FIN, as1, ad1, gb, a_s, a_d);
  k_agg<<<NN, 256, 0, stream>>>(gb, col, offs, a_s, a_d, b1, ab);

  // GAT layer 2
  k_gemm_n<<<NN/64, 256, 0, stream>>>(ab, Wt2, HC, as2, ad2, gb, a_s, a_d);
  k_agg<<<NN, 256, 0, stream>>>(gb, col, offs, a_s, a_d, b2, ab);  // ab = xg (bf16)

  // encoder head
  k_gemm_big<<<dim3(HIDD/BNB, NSPLIT), 256, 0, stream>>>(ab, We, part);
  k_reduce<<<BB*HIDD/256, 256, 0, stream>>>(part, be, y);
  k_bn<<<HIDD, 64, 0, stream>>>(y, ybn);
  k_ln<<<BB, 512, 0, stream>>>(ybn, yln);
  k_heads<<<BB, 128, 0, stream>>>(yln, Wmu, bmu, Wvar, bvar, (float*)d_out);
}

// Round 5
// 381.185 us; speedup vs baseline: 3.0006x; 1.1740x over previous
//
#include <hip/hip_runtime.h>
#include <math.h>

#define NN 32000
#define FIN 128
#define HC 256      // HEADS*CH
#define NH 4        // heads
#define HIDD 512
#define BB 64       // batch
#define ZD 64
#define NSPLIT 250  // big-gemm K splits
#define KBCH 512    // K rows per split (250*512 = 128000)
#define BNB 128     // big-gemm N per block (4 n-groups)

typedef __bf16 bf16x8 __attribute__((ext_vector_type(8)));
typedef float f32x4 __attribute__((ext_vector_type(4)));
typedef unsigned int uint;

__device__ inline float lrelu(float x){ return x > 0.f ? x : 0.2f*x; }
__device__ inline unsigned short f2b(float f){           // fp32 -> bf16 RNE
  uint u = __float_as_uint(f);
  return (unsigned short)((u + 0x7FFFu + ((u >> 16) & 1u)) >> 16);
}
__device__ inline float b2f(unsigned short b){ return __uint_as_float(((uint)b) << 16); }

// ---- edge_index dtype detection (int64 vs int32) ----
__global__ void k_detect(const void* ei, int* flag){
  int t = threadIdx.x;
  int v = ((const int*)ei)[2*t + 1];
  unsigned long long b = __ballot(v == 0);
  if (t == 0) *flag = (b == ~0ULL) ? 1 : 0;
}

__global__ void k_convert(const void* ei, const int* __restrict__ flag,
                          int* __restrict__ out, int n){
  int i = blockIdx.x*256 + threadIdx.x;
  if (i >= n) return;
  if (*flag) out[i] = (int)(((const long long*)ei)[i]);
  else       out[i] = ((const int*)ei)[i];
}

// ---- fp32 -> bf16 elementwise ----
__global__ void k_cvt(const float* __restrict__ in, unsigned short* __restrict__ out, int n){
  int i = blockIdx.x*256 + threadIdx.x;
  if (i < n) out[i] = f2b(in[i]);
}

// ---- W [K][256] fp32 -> Wt [256][K] bf16 (transposed for B-frag reads) ----
__global__ void k_cvtT(const float* __restrict__ Wm, unsigned short* __restrict__ Wt, int K){
  int n = blockIdx.x, k = threadIdx.x;
  Wt[n*K + k] = f2b(Wm[k*HC + n]);
}

__global__ void k_hist(const int* __restrict__ dst, int* counts, int E){
  int i = blockIdx.x*256 + threadIdx.x;
  if (i < E) atomicAdd(&counts[dst[i]], 1);
}

__global__ __launch_bounds__(1024) void k_scan(const int* __restrict__ counts,
    int* __restrict__ offs, int* __restrict__ cursor, int n){
  __shared__ int sums[1024];
  int t = threadIdx.x;
  const int CHK = 32;
  int base = t * CHK;
  int s = 0;
  for (int i = 0; i < CHK; i++){ int idx = base + i; if (idx < n) s += counts[idx]; }
  sums[t] = s;
  __syncthreads();
  for (int off = 1; off < 1024; off <<= 1){
    int v = (t >= off) ? sums[t - off] : 0;
    __syncthreads();
    sums[t] += v;
    __syncthreads();
  }
  int run = (t == 0) ? 0 : sums[t-1];
  for (int i = 0; i < CHK; i++){
    int idx = base + i;
    if (idx < n){ offs[idx] = run; cursor[idx] = run; run += counts[idx]; }
  }
  if (t == 1023) offs[n] = sums[1023];
}

__global__ void k_fill(const int* __restrict__ src, const int* __restrict__ dst,
                       int* __restrict__ cursor, int* __restrict__ col, int E){
  int i = blockIdx.x*256 + threadIdx.x;
  if (i < E){
    int pos = atomicAdd(&cursor[dst[i]], 1);
    col[pos] = src[i];
  }
}

// ---- node GEMM (MFMA bf16): out[M,256] = A[M,K] @ Wt^T, fused attention dots ----
__global__ __launch_bounds__(256) void k_gemm_n(const unsigned short* __restrict__ A,
    const unsigned short* __restrict__ Wt, int K,
    const float* __restrict__ ws, const float* __restrict__ wd,
    unsigned short* __restrict__ out, float* __restrict__ a_s, float* __restrict__ a_d){
  __shared__ unsigned short As[64][40];
  __shared__ unsigned short Bs[256][40];
  int m0 = blockIdx.x * 64;
  int t = threadIdx.x;
  int w = t >> 6, lane = t & 63, l15 = lane & 15, l16 = lane >> 4;
  f32x4 acc[16];
  #pragma unroll
  for (int c = 0; c < 16; c++) acc[c] = (f32x4){0.f,0.f,0.f,0.f};

  for (int k0 = 0; k0 < K; k0 += 32){
    { // stage A: [64 rows][32 k] bf16
      int row = t >> 2, ko = (t & 3) * 8;
      *(uint4*)&As[row][ko] = *(const uint4*)&A[(size_t)(m0 + row)*K + k0 + ko];
    }
    { // stage B: [256 cols][32 k] bf16 (Wt already [n][k])
      #pragma unroll
      for (int p = 0; p < 4; p++)
        *(uint4*)&Bs[t][p*8] = *(const uint4*)&Wt[(size_t)t*K + k0 + p*8];
    }
    __syncthreads();
    bf16x8 af = *(const bf16x8*)&As[w*16 + l15][l16*8];
    #pragma unroll
    for (int c = 0; c < 16; c++){
      bf16x8 bfr = *(const bf16x8*)&Bs[c*16 + l15][l16*8];
      acc[c] = __builtin_amdgcn_mfma_f32_16x16x32_bf16(af, bfr, acc[c], 0, 0, 0);
    }
    __syncthreads();
  }

  // epilogue: store bf16 h, and per-head dots a_s = h·att_src, a_d = h·att_dst
  #pragma unroll
  for (int r = 0; r < 4; r++){
    int row = m0 + w*16 + l16*4 + r;
    float hs[NH] = {0,0,0,0}, hd[NH] = {0,0,0,0};
    #pragma unroll
    for (int c = 0; c < 16; c++){
      float v = acc[c][r];
      int colc = c*16 + l15;
      out[(size_t)row*HC + colc] = f2b(v);
      hs[c>>2] += v * ws[colc];
      hd[c>>2] += v * wd[colc];
    }
    #pragma unroll
    for (int h = 0; h < NH; h++){
      float s = hs[h], d = hd[h];
      #pragma unroll
      for (int o = 1; o < 16; o <<= 1){ s += __shfl_xor(s, o); d += __shfl_xor(d, o); }
      if (l15 == h){ a_s[row*NH + h] = s; a_d[row*NH + h] = d; }
    }
  }
}

// ---- fused GAT edge phase + aggregation: ONE WAVE per node, no LDS, no barriers.
// lane l: head h = l>>4, q = l&15, channels 4l..4l+3 (ushort4 gathers).
// max: strided over edges by q within head group, then 4-step shfl_xor reduce.
// aggregate: all lanes iterate all edges; p recomputed per lane (exp is cheap);
// denominator needs no reduction (every lane sums all edges).
__global__ __launch_bounds__(256) void k_agg(const unsigned short* __restrict__ hp,
    const int* __restrict__ col, const int* __restrict__ offs,
    const float* __restrict__ a_s, const float* __restrict__ a_d,
    const float* __restrict__ bias, unsigned short* __restrict__ outb){
  int n = blockIdx.x*4 + (threadIdx.x >> 6);
  if (n >= NN) return;
  int lane = threadIdx.x & 63;
  int h = lane >> 4, q = lane & 15;
  int c0 = lane * 4;
  int b0 = offs[n], b1 = offs[n+1];
  float adh = a_d[n*NH + h];
  float se  = lrelu(a_s[n*NH + h] + adh);
  float m = se;
  for (int i = b0 + q; i < b1; i += 16)
    m = fmaxf(m, lrelu(a_s[col[i]*NH + h] + adh));
  #pragma unroll
  for (int o = 1; o < 16; o <<= 1) m = fmaxf(m, __shfl_xor(m, o));
  float pself = expf(se - m);
  float den = pself;
  float acc0 = 0.f, acc1 = 0.f, acc2 = 0.f, acc3 = 0.f;
  #pragma unroll 4
  for (int i = b0; i < b1; i++){
    int s = col[i];
    float p = expf(lrelu(a_s[s*NH + h] + adh) - m);
    den += p;
    ushort4 v = *(const ushort4*)&hp[(size_t)s*HC + c0];
    acc0 = fmaf(p, b2f(v.x), acc0);
    acc1 = fmaf(p, b2f(v.y), acc1);
    acc2 = fmaf(p, b2f(v.z), acc2);
    acc3 = fmaf(p, b2f(v.w), acc3);
  }
  ushort4 hv = *(const ushort4*)&hp[(size_t)n*HC + c0];
  float r = 1.f / den;
  ushort4 ov;
  ov.x = f2b(fmaxf((pself*b2f(hv.x) + acc0)*r + bias[c0+0], 0.f));
  ov.y = f2b(fmaxf((pself*b2f(hv.y) + acc1)*r + bias[c0+1], 0.f));
  ov.z = f2b(fmaxf((pself*b2f(hv.z) + acc2)*r + bias[c0+2], 0.f));
  ov.w = f2b(fmaxf((pself*b2f(hv.w) + acc3)*r + bias[c0+3], 0.f));
  *(ushort4*)&outb[(size_t)n*HC + c0] = ov;
}

// ---- big GEMM (MFMA bf16), LDS double-buffered, 1 barrier/K-step ----
// grid (4 n-blocks of 128, 250 k-chunks); block 256 thr = 4 waves.
__global__ __launch_bounds__(256) void k_gemm_big(const unsigned short* __restrict__ xg,
    const float* __restrict__ We, float* __restrict__ part){
  __shared__ unsigned short As[2][64][40];
  __shared__ unsigned short Bs[2][BNB][40];
  int n0 = blockIdx.x * BNB;
  int kc = blockIdx.y;
  int kbase = kc * KBCH;
  int t = threadIdx.x, w = t >> 6, lane = t & 63, l15 = lane & 15, l16 = lane >> 4;
  int cc = t & (BNB-1);
  int khalf = t >> 7;
  int arow = t >> 2, ako = (t & 3) * 8;
  const float* bptr = We + (size_t)(kbase + khalf*16)*HIDD + n0 + cc;
  const unsigned short* aptr = xg + (size_t)arow*128000 + kbase + ako;
  f32x4 acc[8];
  #pragma unroll
  for (int c = 0; c < 8; c++) acc[c] = (f32x4){0.f,0.f,0.f,0.f};

  float rv[16]; uint4 a4;
  #pragma unroll
  for (int mm = 0; mm < 16; mm++) rv[mm] = bptr[(size_t)mm*HIDD];
  a4 = *(const uint4*)aptr;

  int p = 0;
  for (int ks = 0; ks < KBCH; ks += 32){
    // write current regs -> LDS[p] (single vmcnt wait covers all loads)
    *(uint4*)&As[p][arow][ako] = a4;
    #pragma unroll
    for (int j = 0; j < 8; j++){
      uint pk = ((uint)f2b(rv[2*j+1]) << 16) | (uint)f2b(rv[2*j]);
      *(uint*)&Bs[p][cc][khalf*16 + 2*j] = pk;
    }
    __syncthreads();
    // issue next K-step loads (overlap with MFMA below + other waves)
    if (ks + 32 < KBCH){
      const float* bp2 = bptr + (size_t)(ks + 32)*HIDD;
      #pragma unroll
      for (int mm = 0; mm < 16; mm++) rv[mm] = bp2[(size_t)mm*HIDD];
      a4 = *(const uint4*)(aptr + ks + 32);
    }
    bf16x8 af = *(const bf16x8*)&As[p][w*16 + l15][l16*8];
    #pragma unroll
    for (int c = 0; c < 8; c++){
      bf16x8 bfr = *(const bf16x8*)&Bs[p][c*16 + l15][l16*8];
      acc[c] = __builtin_amdgcn_mfma_f32_16x16x32_bf16(af, bfr, acc[c], 0, 0, 0);
    }
    p ^= 1;
  }
  float* pbase = part + (size_t)kc*BB*HIDD;
  #pragma unroll
  for (int r = 0; r < 4; r++){
    int row = w*16 + l16*4 + r;
    #pragma unroll
    for (int c = 0; c < 8; c++)
      pbase[row*HIDD + n0 + c*16 + l15] = acc[c][r];
  }
}

// ---- reduce partials + bias ----
__global__ void k_reduce(const float* __restrict__ part, const float* __restrict__ be,
                         float* __restrict__ y){
  int o = blockIdx.x*256 + threadIdx.x;
  float s = 0.f;
  #pragma unroll 5
  for (int k = 0; k < NSPLIT; k++) s += part[(size_t)k*BB*HIDD + o];
  y[o] = s + be[o & (HIDD-1)];
}

// BatchNorm over batch axis
__global__ __launch_bounds__(64) void k_bn(const float* __restrict__ y,
    float* __restrict__ ybn){
  int colb = blockIdx.x, r = threadIdx.x;
  float v = y[(size_t)r*HIDD + colb];
  float s = v, s2 = v*v;
  #pragma unroll
  for (int o = 32; o; o >>= 1){ s += __shfl_down(s, o); s2 += __shfl_down(s2, o); }
  s = __shfl(s, 0); s2 = __shfl(s2, 0);
  float mean = s * (1.f/BB);
  float var = s2 * (1.f/BB) - mean*mean;
  ybn[(size_t)r*HIDD + colb] = (v - mean) * rsqrtf(var + 1e-3f);
}

// LayerNorm + relu
__global__ __launch_bounds__(512) void k_ln(const float* __restrict__ ybn,
    float* __restrict__ yln){
  __shared__ float ssum[8], ssq[8];
  int row = blockIdx.x, t = threadIdx.x;
  float v = ybn[(size_t)row*HIDD + t];
  float s = v, s2 = v*v;
  #pragma unroll
  for (int o = 32; o; o >>= 1){ s += __shfl_down(s, o); s2 += __shfl_down(s2, o); }
  if ((t & 63) == 0){ ssum[t>>6] = s; ssq[t>>6] = s2; }
  __syncthreads();
  if (t == 0){
    float S = 0, S2 = 0;
    for (int i = 0; i < 8; i++){ S += ssum[i]; S2 += ssq[i]; }
    ssum[0] = S; ssq[0] = S2;
  }
  __syncthreads();
  float mean = ssum[0] * (1.f/HIDD);
  float var = ssq[0] * (1.f/HIDD) - mean*mean;
  yln[(size_t)row*HIDD + t] = fmaxf((v - mean) * rsqrtf(var + 1e-5f), 0.f);
}

__global__ __launch_bounds__(128) void k_heads(const float* __restrict__ yln,
    const float* __restrict__ Wmu, const float* __restrict__ bmu,
    const float* __restrict__ Wvar, const float* __restrict__ bvar,
    float* __restrict__ out){
  __shared__ float yrow[HIDD];
  int b = blockIdx.x, t = threadIdx.x;
  for (int i = t; i < HIDD; i += 128) yrow[i] = yln[(size_t)b*HIDD + i];
  __syncthreads();
  if (t < ZD){
    float acc = bmu[t];
    for (int k = 0; k < HIDD; k++) acc = fmaf(yrow[k], Wmu[(size_t)k*ZD + t], acc);
    out[b*ZD + t] = acc;
  } else {
    int j = t - ZD;
    float acc = bvar[j];
    for (int k = 0; k < HIDD; k++) acc = fmaf(yrow[k], Wvar[(size_t)k*ZD + j], acc);
    out[BB*ZD + b*ZD + j] = expf(acc) + 1e-4f;
  }
}

extern "C" void kernel_launch(void* const* d_in, const int* in_sizes, int n_in,
                              void* d_out, int out_size, void* d_ws, size_t ws_size,
                              hipStream_t stream){
  const float* x    = (const float*)d_in[0];
  const float* W1   = (const float*)d_in[1];
  const float* as1  = (const float*)d_in[2];
  const float* ad1  = (const float*)d_in[3];
  const float* b1   = (const float*)d_in[4];
  const float* W2   = (const float*)d_in[5];
  const float* as2  = (const float*)d_in[6];
  const float* ad2  = (const float*)d_in[7];
  const float* b2   = (const float*)d_in[8];
  const float* We   = (const float*)d_in[9];
  const float* be   = (const float*)d_in[10];
  const float* Wmu  = (const float*)d_in[11];
  const float* bmu  = (const float*)d_in[12];
  const float* Wvar = (const float*)d_in[13];
  const float* bvar = (const float*)d_in[14];
  const void*  ei   = d_in[15];
  int E = in_sizes[15] / 2;

  char* w = (char*)d_ws;
  auto alloc = [&](size_t bytes)->void*{
    void* p = (void*)w; w += (bytes + 255) & ~(size_t)255; return p;
  };
  unsigned short* gb   = (unsigned short*)alloc((size_t)NN*HC*2);
  unsigned short* ab   = (unsigned short*)alloc((size_t)NN*HC*2);
  unsigned short* xb   = (unsigned short*)alloc((size_t)NN*FIN*2);
  unsigned short* Wt1  = (unsigned short*)alloc((size_t)HC*FIN*2);
  unsigned short* Wt2  = (unsigned short*)alloc((size_t)HC*HC*2);
  float*    a_s    = (float*)alloc((size_t)NN*NH*4);
  float*    a_d    = (float*)alloc((size_t)NN*NH*4);
  int*      counts = (int*)alloc((size_t)NN*4);
  int*      offs   = (int*)alloc((size_t)(NN+1)*4);
  int*      cursor = (int*)alloc((size_t)NN*4);
  int*      col    = (int*)alloc((size_t)E*4);
  int*      econv  = (int*)alloc((size_t)2*E*4);
  int*      flag   = (int*)alloc(256);
  float*    part   = (float*)alloc((size_t)NSPLIT*BB*HIDD*4);
  float*    y      = (float*)alloc((size_t)BB*HIDD*4);
  float*    ybn    = (float*)alloc((size_t)BB*HIDD*4);
  float*    yln    = (float*)alloc((size_t)BB*HIDD*4);

  k_detect<<<1, 64, 0, stream>>>(ei, flag);
  k_convert<<<(2*E + 255)/256, 256, 0, stream>>>(ei, flag, econv, 2*E);
  const int* src  = econv;
  const int* dstp = econv + E;

  // CSR (graph-only; shared by both layers)
  hipMemsetAsync(counts, 0, (size_t)NN*4, stream);
  k_hist<<<(E + 255)/256, 256, 0, stream>>>(dstp, counts, E);
  k_scan<<<1, 1024, 0, stream>>>(counts, offs, cursor, NN);
  k_fill<<<(E + 255)/256, 256, 0, stream>>>(src, dstp, cursor, col, E);

  // bf16 conversions
  k_cvt<<<(NN*FIN + 255)/256, 256, 0, stream>>>(x, xb, NN*FIN);
  k_cvtT<<<HC, FIN, 0, stream>>>(W1, Wt1, FIN);
  k_cvtT<<<HC, HC,  0, stream>>>(W2, Wt2, HC);

  // GAT layer 1
  k_gemm_n<<<NN/64, 256, 0, stream>>>(xb, Wt1, FIN, as1, ad1, gb, a_s, a_d);
  k_agg<<<NN/4, 256, 0, stream>>>(gb, col, offs, a_s, a_d, b1, ab);

  // GAT layer 2
  k_gemm_n<<<NN/64, 256, 0, stream>>>(ab, Wt2, HC, as2, ad2, gb, a_s, a_d);
  k_agg<<<NN/4, 256, 0, stream>>>(gb, col, offs, a_s, a_d, b2, ab);  // ab = xg (bf16)

  // encoder head
  k_gemm_big<<<dim3(HIDD/BNB, NSPLIT), 256, 0, stream>>>(ab, We, part);
  k_reduce<<<BB*HIDD/256, 256, 0, stream>>>(part, be, y);
  k_bn<<<HIDD, 64, 0, stream>>>(y, ybn);
  k_ln<<<BB, 512, 0, stream>>>(ybn, yln);
  k_heads<<<BB, 128, 0, stream>>>(yln, Wmu, bmu, Wvar, bvar, (float*)d_out);
}